// Round 13
// baseline (637.183 us; speedup 1.0000x reference)
//
#include <hip/hip_runtime.h>
#include <hip/hip_bf16.h>
#include <math.h>

#define NN 20000
#define EE 256000
#define HH 128
#define NGAUSS 150

typedef __attribute__((ext_vector_type(8))) short bf16x8;
typedef __attribute__((ext_vector_type(4))) float f32x4;
typedef __attribute__((ext_vector_type(16))) float f32x16;

__device__ __forceinline__ short f2bf(float f) {
  unsigned u = __builtin_bit_cast(unsigned, f);
  u += 0x7FFFu + ((u >> 16) & 1u);
  return (short)(u >> 16);
}
__device__ __forceinline__ float bf2f(short s) {
  unsigned u = ((unsigned)(unsigned short)s) << 16;
  return __builtin_bit_cast(float, u);
}
// cheap ShiftedSoftplus: max(x,0) + log(1+exp(-|x|)) - log2, native exp/log
__device__ __forceinline__ float sspf(float x) {
  float t = __expf(-fabsf(x));
  return fmaxf(x, 0.f) + __logf(1.f + t) - 0.69314718055994531f;
}

// ---- weight packing, single bf16 plane ----
// mode 0 (16x16x32): k = kt*32 + (lane>>4)*8 + j, n = nt*16 + (lane&15)
// mode 1 (32x32x16): k = kt*16 + (lane>>5)*8 + j, n = nt*32 + (lane&31)
struct PackDesc { const float* src; short* dst; int Kreal; int KT; int NT; int mode; int end; };
struct PackArgs { PackDesc d[24]; };

__global__ void packall_kernel(PackArgs a, int total) {
  int idx = blockIdx.x * 256 + threadIdx.x;
  if (idx >= total) return;
  int i = 0, start = 0;
  while (idx >= a.d[i].end) { start = a.d[i].end; ++i; }
  int local = idx - start;
  const float* src = a.d[i].src;
  short* dst = a.d[i].dst;
  int Kreal = a.d[i].Kreal, NT = a.d[i].NT, mode = a.d[i].mode;
  int j = local & 7;
  int lane = (local >> 3) & 63;
  int tile = local >> 9;
  int nt = tile % NT, kt = tile / NT;
  int k, n, N;
  if (mode == 1) {
    k = kt * 16 + (lane >> 5) * 8 + j; n = nt * 32 + (lane & 31); N = NT * 32;
  } else {
    k = kt * 32 + (lane >> 4) * 8 + j; n = nt * 16 + (lane & 15); N = NT * 16;
  }
  float w = (k < Kreal) ? src[(size_t)k * N + n] : 0.f;
  dst[local] = f2bf(w);
}

// ---- 16x16x32 LDS-A x packed-B GEMM, single-plane (node/readout kernels) ----
// NOTE (r9): LDS tile stride MUST be a multiple of 8 shorts (16B) or the
// b128 A-reads misalign and split (+42% measured).
template <int KT, int NTW, int JSTEP = 1>
__device__ __forceinline__ void gemm_tile(const short* __restrict__ A, int as,
                                          const short* __restrict__ pack, int ktBase,
                                          int NT, int lane, int wave,
                                          f32x4 (&acc)[NTW][4]) {
  constexpr int WSTEP = (JSTEP == 1) ? NTW : 1;
  const int arow = lane & 15, agrp = lane >> 4;
  const short* abase = A + arow * as + agrp * 8;
  const short* bbase = pack + (size_t)ktBase * NT * 512 + (size_t)lane * 8;
  const int nt0 = wave * WSTEP;
  bf16x8 af[4], bh[NTW];
#pragma unroll
  for (int rg = 0; rg < 4; ++rg) af[rg] = *(const bf16x8*)(abase + rg * 16 * as);
#pragma unroll
  for (int j = 0; j < NTW; ++j)
    bh[j] = *(const bf16x8*)(bbase + (size_t)(nt0 + j * JSTEP) * 512);
#pragma unroll
  for (int kt = 0; kt < KT; ++kt) {
    bf16x8 naf[4], nbh[NTW];
    if (kt + 1 < KT) {
#pragma unroll
      for (int rg = 0; rg < 4; ++rg)
        naf[rg] = *(const bf16x8*)(abase + rg * 16 * as + (kt + 1) * 32);
#pragma unroll
      for (int j = 0; j < NTW; ++j)
        nbh[j] = *(const bf16x8*)(bbase + (size_t)((kt + 1) * NT + nt0 + j * JSTEP) * 512);
    }
#pragma unroll
    for (int j = 0; j < NTW; ++j)
#pragma unroll
      for (int rg = 0; rg < 4; ++rg)
        acc[j][rg] = __builtin_amdgcn_mfma_f32_16x16x32_bf16(af[rg], bh[j], acc[j][rg], 0, 0, 0);
    if (kt + 1 < KT) {
#pragma unroll
      for (int rg = 0; rg < 4; ++rg) af[rg] = naf[rg];
#pragma unroll
      for (int j = 0; j < NTW; ++j) bh[j] = nbh[j];
    }
  }
}

// ---- 32x32x16 LDS-A x packed-B GEMM, single-plane (edge kernel) ----
// A layout: row = mtile*32 + (lane&31), k = kt*16 + (lane>>5)*8 + j
// One b128 A-read per kt (vs 4 for 16x16) — halves A-side LDS traffic.
// SPLIT: alternate kt parity into accB (2 independent MFMA chains for NTW=1);
// caller sums accA+accB in the epilogue.
template <int KT, int NTW, int JSTEP, bool SPLIT>
__device__ __forceinline__ void gemm32(const short* __restrict__ A, int as,
                                       const short* __restrict__ pack, int ktBase,
                                       int NT, int lane, int cwave, int mtile,
                                       f32x16 (&accA)[NTW], f32x16 (&accB)[NTW]) {
  constexpr int WSTEP = (JSTEP == 1) ? NTW : 1;
  const int a32 = lane & 31, kg = lane >> 5;
  const short* abase = A + (mtile * 32 + a32) * as + kg * 8;
  const short* bbase = pack + (size_t)ktBase * NT * 512 + (size_t)lane * 8;
  const int nt0 = cwave * WSTEP;
  bf16x8 af, bh[NTW];
  af = *(const bf16x8*)abase;
#pragma unroll
  for (int j = 0; j < NTW; ++j)
    bh[j] = *(const bf16x8*)(bbase + (size_t)(nt0 + j * JSTEP) * 512);
#pragma unroll
  for (int kt = 0; kt < KT; ++kt) {
    bf16x8 naf, nbh[NTW];
    if (kt + 1 < KT) {
      naf = *(const bf16x8*)(abase + (kt + 1) * 16);
#pragma unroll
      for (int j = 0; j < NTW; ++j)
        nbh[j] = *(const bf16x8*)(bbase + (size_t)((kt + 1) * NT + nt0 + j * JSTEP) * 512);
    }
    if (SPLIT && (kt & 1)) {
#pragma unroll
      for (int j = 0; j < NTW; ++j)
        accB[j] = __builtin_amdgcn_mfma_f32_32x32x16_bf16(af, bh[j], accB[j], 0, 0, 0);
    } else {
#pragma unroll
      for (int j = 0; j < NTW; ++j)
        accA[j] = __builtin_amdgcn_mfma_f32_32x32x16_bf16(af, bh[j], accA[j], 0, 0, 0);
    }
    if (kt + 1 < KT) {
      af = naf;
#pragma unroll
      for (int j = 0; j < NTW; ++j) bh[j] = nbh[j];
    }
  }
}

// stage 16 f32 -> 16 bf16 (two uint4 stores)
__device__ __forceinline__ void cvt16(const float4* __restrict__ src, short* dst) {
#pragma unroll
  for (int v = 0; v < 2; ++v) {
    float4 f0 = src[2 * v], f1 = src[2 * v + 1];
    union { short s[8]; uint4 u; } tm;
    tm.s[0] = f2bf(f0.x); tm.s[1] = f2bf(f0.y); tm.s[2] = f2bf(f0.z); tm.s[3] = f2bf(f0.w);
    tm.s[4] = f2bf(f1.x); tm.s[5] = f2bf(f1.y); tm.s[6] = f2bf(f1.z); tm.s[7] = f2bf(f1.w);
    *(uint4*)(dst + v * 8) = tm.u;
  }
}

// embed + first-layer cf nodegemm fused: h = bf16(emb[z]); hcf = h @ cf0
__global__ __launch_bounds__(512, 4) void embedgemm_kernel(
    const int* __restrict__ z, const float* __restrict__ emb,
    const short* __restrict__ pk, short* __restrict__ h, short* __restrict__ hcf) {
  __shared__ short A[64 * 136];
  const int t = threadIdx.x, wave = t >> 6, lane = t & 63;
  const int arow = lane & 15, agrp = lane >> 4;
  const int n0 = blockIdx.x * 64;
  {
    int el = t >> 3, q = t & 7;
    int n = n0 + el;
    short* dst = A + el * 136 + q * 16;
    if (n < NN) {
      const float4* src = (const float4*)(emb + (size_t)z[n] * HH + q * 16);
      union { short s[16]; uint4 u[2]; } tm;
#pragma unroll
      for (int v = 0; v < 2; ++v) {
        float4 f0 = src[2 * v], f1 = src[2 * v + 1];
        tm.s[v * 8 + 0] = f2bf(f0.x); tm.s[v * 8 + 1] = f2bf(f0.y);
        tm.s[v * 8 + 2] = f2bf(f0.z); tm.s[v * 8 + 3] = f2bf(f0.w);
        tm.s[v * 8 + 4] = f2bf(f1.x); tm.s[v * 8 + 5] = f2bf(f1.y);
        tm.s[v * 8 + 6] = f2bf(f1.z); tm.s[v * 8 + 7] = f2bf(f1.w);
      }
      *(uint4*)dst = tm.u[0]; *(uint4*)(dst + 8) = tm.u[1];
      uint4* hg = (uint4*)(h + (size_t)n * HH + q * 16);
      hg[0] = tm.u[0]; hg[1] = tm.u[1];
    } else {
      uint4 zz = {0u, 0u, 0u, 0u};
      *(uint4*)dst = zz; *(uint4*)(dst + 8) = zz;
    }
  }
  __syncthreads();
  f32x4 zv = {0.f, 0.f, 0.f, 0.f};
  f32x4 acc[1][4];
#pragma unroll
  for (int rg = 0; rg < 4; ++rg) acc[0][rg] = zv;
  gemm_tile<4, 1>(A, 136, pk, 0, 8, lane, wave, acc);
  int col = wave * 16 + arow;
#pragma unroll
  for (int rg = 0; rg < 4; ++rg)
#pragma unroll
    for (int r = 0; r < 4; ++r) {
      int n = n0 + rg * 16 + agrp * 4 + r;
      if (n < NN) hcf[(size_t)n * HH + col] = f2bf(acc[0][rg][r]);
    }
}

// h += ssp(m @ st1) @ st2 ; optionally fused hcf = h_new @ cf_{i+1}
// FUSE also re-zeroes m in place of a separate memset
template <bool FUSE>
__global__ __launch_bounds__(512, 4) void state_kernel(
    short* __restrict__ h, float* __restrict__ m,
    const short* __restrict__ p1, const short* __restrict__ p2,
    const short* __restrict__ pcf, short* __restrict__ hcf) {
  __shared__ short A[64 * 136];
  __shared__ short T[64 * 136];
  const int t = threadIdx.x, wave = t >> 6, lane = t & 63;
  const int arow = lane & 15, agrp = lane >> 4;
  const int n0 = blockIdx.x * 64;
  {
    int el = t >> 3, q = t & 7;
    int n = n0 + el;
    short* dst = A + el * 136 + q * 16;
    if (n < NN) {
      float* msrc = m + (size_t)n * HH + q * 16;
      cvt16((const float4*)msrc, dst);
      if (FUSE) {
        float4 z4 = {0.f, 0.f, 0.f, 0.f};
        float4* mz = (float4*)msrc;
        mz[0] = z4; mz[1] = z4; mz[2] = z4; mz[3] = z4;
      }
    } else {
      uint4 zz = {0u, 0u, 0u, 0u};
      *(uint4*)dst = zz; *(uint4*)(dst + 8) = zz;
    }
  }
  __syncthreads();
  f32x4 zv = {0.f, 0.f, 0.f, 0.f};
  f32x4 acc[1][4];
#pragma unroll
  for (int rg = 0; rg < 4; ++rg) acc[0][rg] = zv;
  gemm_tile<4, 1>(A, 136, p1, 0, 8, lane, wave, acc);
  int col = wave * 16 + arow;
#pragma unroll
  for (int rg = 0; rg < 4; ++rg)
#pragma unroll
    for (int r = 0; r < 4; ++r) {
      int rowl = rg * 16 + agrp * 4 + r;
      T[rowl * 136 + col] = f2bf(sspf(acc[0][rg][r]));
    }
  __syncthreads();
  // hoist residual h loads (latency cover for the p2 gemm)
  short hold[16];
#pragma unroll
  for (int rg = 0; rg < 4; ++rg)
#pragma unroll
    for (int r = 0; r < 4; ++r) {
      int n = n0 + rg * 16 + agrp * 4 + r;
      hold[rg * 4 + r] = (n < NN) ? h[(size_t)n * HH + col] : (short)0;
    }
  f32x4 acc2[1][4];
#pragma unroll
  for (int rg = 0; rg < 4; ++rg) acc2[0][rg] = zv;
  gemm_tile<4, 1>(T, 136, p2, 0, 8, lane, wave, acc2);
#pragma unroll
  for (int rg = 0; rg < 4; ++rg)
#pragma unroll
    for (int r = 0; r < 4; ++r) {
      int rowl = rg * 16 + agrp * 4 + r;
      int n = n0 + rowl;
      short nb = f2bf(bf2f(hold[rg * 4 + r]) + acc2[0][rg][r]);
      if (n < NN) h[(size_t)n * HH + col] = nb;
      if (FUSE) A[rowl * 136 + col] = (n < NN) ? nb : (short)0;
    }
  if (FUSE) {
    __syncthreads();
    f32x4 acc3[1][4];
#pragma unroll
    for (int rg = 0; rg < 4; ++rg) acc3[0][rg] = zv;
    gemm_tile<4, 1>(A, 136, pcf, 0, 8, lane, wave, acc3);
#pragma unroll
    for (int rg = 0; rg < 4; ++rg)
#pragma unroll
      for (int r = 0; r < 4; ++r) {
        int n = n0 + rg * 16 + agrp * 4 + r;
        if (n < NN) hcf[(size_t)n * HH + col] = f2bf(acc3[0][rg][r]);
      }
  }
}

// fused per-layer edge pipeline: 32x32x16 MFMA, single-plane weights,
// r10 barrier skeleton, ALL LDS strides 16B-aligned (168=336B, 136=272B).
template <bool L0, bool WRITE_E>
__global__ __launch_bounds__(512, 4) void edge_kernel(
    const short* __restrict__ h, const short* __restrict__ hcf,
    const int* __restrict__ ei, const float* __restrict__ pos,
    const short* __restrict__ ein, short* __restrict__ eout,
    const short* __restrict__ w1p, const float* __restrict__ b1,
    const short* __restrict__ w2p, const float* __restrict__ b2,
    const short* __restrict__ f1p, const float* __restrict__ fb1,
    const short* __restrict__ f2p, const float* __restrict__ fb2,
    float* __restrict__ m, float gcoeff, float gstep) {
  __shared__ short SBUF[64 * 168];   // staging (stride 168) / e-values (stride 136)
  __shared__ short ACT[64 * 136];    // fc1 half-activations / filter1 output
  __shared__ int RIDX[64], CIDX[64];
  const int t = threadIdx.x;
  const int wave = t >> 6, lane = t & 63;
  const int a32 = lane & 31, kg = lane >> 5;
  const int mtile = wave >> 2, cwave = wave & 3;
  const int e0 = blockIdx.x * 64;

  if (t < 64) RIDX[t] = ei[e0 + t];
  else if (t < 128) CIDX[t - 64] = ei[EE + e0 + t - 64];
  __syncthreads();

  const int el = t >> 3, q = t & 7;
  const f32x16 z16 = {0.f, 0.f, 0.f, 0.f, 0.f, 0.f, 0.f, 0.f,
                      0.f, 0.f, 0.f, 0.f, 0.f, 0.f, 0.f, 0.f};
  f32x16 acc1[2];   // [half]; nt = cwave + 4*half ; (NTW=2 -> already 2 chains)
  acc1[0] = z16; acc1[1] = z16;

  // ---- fc1 over three K-splits: h[col] (0:128), h[row] (128:256), e (256:) ----
  for (int split = 0; split < 3; ++split) {
    if (split < 2) {
      int node = (split == 0) ? CIDX[el] : RIDX[el];
      const uint4* src = (const uint4*)(h + (size_t)node * HH + q * 16);
      uint4* dst = (uint4*)(SBUF + el * 168 + q * 16);
      dst[0] = src[0]; dst[1] = src[1];
    } else if (L0) {
      int rn = RIDX[el], cn = CIDX[el];
      float dx = pos[rn * 3 + 0] - pos[cn * 3 + 0];
      float dy = pos[rn * 3 + 1] - pos[cn * 3 + 1];
      float dz = pos[rn * 3 + 2] - pos[cn * 3 + 2];
      float d = sqrtf(dx * dx + dy * dy + dz * dz);
#pragma unroll
      for (int i2 = 0; i2 < 20; ++i2) {
        int k = q * 20 + i2;
        float val = 0.f;
        if (k < NGAUSS) { float u = d - (float)k * gstep; val = __expf(gcoeff * u * u); }
        SBUF[el * 168 + k] = f2bf(val);
      }
    } else {
      const uint4* src = (const uint4*)(ein + (size_t)(e0 + el) * HH + q * 16);
      uint4* dst = (uint4*)(SBUF + el * 168 + q * 16);
      dst[0] = src[0]; dst[1] = src[1];
    }
    __syncthreads();
    if (split < 2)
      gemm32<8, 2, 4, false>(SBUF, 168, w1p, split * 8, 8, lane, cwave, mtile, acc1, acc1);
    else if (L0)
      gemm32<10, 2, 4, false>(SBUF, 168, w1p, 16, 8, lane, cwave, mtile, acc1, acc1);
    else
      gemm32<8, 2, 4, false>(SBUF, 168, w1p, 16, 8, lane, cwave, mtile, acc1, acc1);
    __syncthreads();
  }

  const int col = cwave * 32 + a32;  // 0..127 (within a half)

  // ---- fc2: 256->128 via two 128-K partials; ACT holds one half at a time ----
  f32x16 acc2A[1], acc2B[1];
  acc2A[0] = z16; acc2B[0] = z16;
#pragma unroll
  for (int half = 0; half < 2; ++half) {
    float bias = b1[half * 128 + col];
#pragma unroll
    for (int reg = 0; reg < 16; ++reg) {
      int rowl = mtile * 32 + (reg & 3) + 8 * (reg >> 2) + 4 * kg;
      ACT[rowl * 136 + col] = f2bf(sspf(acc1[half][reg] + bias));
    }
    __syncthreads();
    gemm32<8, 1, 1, true>(ACT, 136, w2p, half * 8, 4, lane, cwave, mtile, acc2A, acc2B);
    __syncthreads();
  }

  // ---- e epilogue: write e to global (if needed) and SBUF (stride 136) ----
  {
    float bias = b2[col];
#pragma unroll
    for (int reg = 0; reg < 16; ++reg) {
      int rowl = mtile * 32 + (reg & 3) + 8 * (reg >> 2) + 4 * kg;
      float ev = acc2A[0][reg] + acc2B[0][reg] + bias;
      short eb = f2bf(ev);
      if (WRITE_E) eout[(size_t)(e0 + rowl) * HH + col] = eb;
      SBUF[rowl * 136 + col] = eb;
    }
  }
  // hoist hcf gather (used only in filter2 epilogue -> covered by filter1 gemm)
  short hvreg[16];
#pragma unroll
  for (int reg = 0; reg < 16; ++reg) {
    int rowl = mtile * 32 + (reg & 3) + 8 * (reg >> 2) + 4 * kg;
    hvreg[reg] = hcf[(size_t)RIDX[rowl] * HH + col];
  }
  __syncthreads();

  // ---- filter1: 128->128, ssp -> ACT (stride 136) ----
  f32x16 acc3A[1], acc3B[1];
  acc3A[0] = z16; acc3B[0] = z16;
  gemm32<8, 1, 1, true>(SBUF, 136, f1p, 0, 4, lane, cwave, mtile, acc3A, acc3B);
  {
    float bias = fb1[col];
#pragma unroll
    for (int reg = 0; reg < 16; ++reg) {
      int rowl = mtile * 32 + (reg & 3) + 8 * (reg >> 2) + 4 * kg;
      ACT[rowl * 136 + col] = f2bf(sspf(acc3A[0][reg] + acc3B[0][reg] + bias));
    }
  }
  __syncthreads();

  // ---- filter2 + modulate + scatter ----
  f32x16 acc4A[1], acc4B[1];
  acc4A[0] = z16; acc4B[0] = z16;
  gemm32<8, 1, 1, true>(ACT, 136, f2p, 0, 4, lane, cwave, mtile, acc4A, acc4B);
  {
    float bias = fb2[col];
#pragma unroll
    for (int reg = 0; reg < 16; ++reg) {
      int rowl = mtile * 32 + (reg & 3) + 8 * (reg >> 2) + 4 * kg;
      float wv = sspf(acc4A[0][reg] + acc4B[0][reg] + bias);
      float hv = bf2f(hvreg[reg]);
      atomicAdd(&m[(size_t)CIDX[rowl] * HH + col], wv * hv);
    }
  }
}

// readout: MFMA per 128-node tile; per-batch LDS accumulation; <=16 global atomics/block
__global__ __launch_bounds__(512, 2) void readout_kernel(
    const short* __restrict__ h, const int* __restrict__ batch,
    const short* __restrict__ pro, const float* __restrict__ b1,
    const float* __restrict__ w2, const float* __restrict__ b2,
    float* __restrict__ out) {
  __shared__ char RAW[128 * 272];  // A[128][136] bf16, later VAL[128][68] f32
  __shared__ float bacc[16];
  short* A = (short*)RAW;
  float* VAL = (float*)RAW;
  const int t = threadIdx.x, wave = t >> 6, lane = t & 63;
  const int arow = lane & 15, agrp = lane >> 4;
  const int n0 = blockIdx.x * 128;
  if (t < 16) bacc[t] = 0.f;
  {
    int row = t >> 2, qq = t & 3;
    int n = n0 + row;
    uint4* dst = (uint4*)(A + row * 136);
    if (n < NN) {
      const uint4* src = (const uint4*)(h + (size_t)n * HH);
#pragma unroll
      for (int v = 0; v < 4; ++v) dst[qq * 4 + v] = src[qq * 4 + v];
    } else {
      uint4 zz = {0u, 0u, 0u, 0u};
#pragma unroll
      for (int v = 0; v < 4; ++v) dst[qq * 4 + v] = zz;
    }
  }
  __syncthreads();
  f32x4 zv = {0.f, 0.f, 0.f, 0.f};
  f32x4 acc[1][4];
#pragma unroll
  for (int rg = 0; rg < 4; ++rg) acc[0][rg] = zv;
  const short* Abase = A + (wave >> 2) * 64 * 136;
  gemm_tile<4, 1>(Abase, 136, pro, 0, 4, lane, wave & 3, acc);
  __syncthreads();  // A dead; VAL aliases it
  {
    int col = (wave & 3) * 16 + arow;
    float bias = b1[col], wv2 = w2[col];
#pragma unroll
    for (int rg = 0; rg < 4; ++rg)
#pragma unroll
      for (int r = 0; r < 4; ++r) {
        int row = (wave >> 2) * 64 + rg * 16 + agrp * 4 + r;
        VAL[row * 68 + col] = sspf(acc[0][rg][r] + bias) * wv2;
      }
  }
  __syncthreads();
  if (t < 128) {
    int n = n0 + t;
    if (n < NN) {
      float s = 0.f;
#pragma unroll 8
      for (int c = 0; c < 64; ++c) s += VAL[t * 68 + c];
      atomicAdd(&bacc[batch[n]], s + b2[0]);
    }
  }
  __syncthreads();
  if (t < 16 && bacc[t] != 0.f) atomicAdd(&out[t], bacc[t]);
}

extern "C" void kernel_launch(void* const* d_in, const int* in_sizes, int n_in,
                              void* d_out, int out_size, void* d_ws, size_t ws_size,
                              hipStream_t stream) {
  const int* z = (const int*)d_in[0];
  const float* pos = (const float*)d_in[1];
  const int* batch = (const int*)d_in[2];
  const int* ei = (const int*)d_in[3];
  const float* emb = (const float*)d_in[4];
  const float* eu0_fc1_w = (const float*)d_in[5];
  const float* eu_fc1_w = (const float*)d_in[6];
  const float* eu_fc1_b = (const float*)d_in[7];
  const float* eu_fc2_w = (const float*)d_in[8];
  const float* eu_fc2_b = (const float*)d_in[9];
  const float* flt_w1 = (const float*)d_in[10];
  const float* flt_b1 = (const float*)d_in[11];
  const float* flt_w2 = (const float*)d_in[12];
  const float* flt_b2 = (const float*)d_in[13];
  const float* cf_w = (const float*)d_in[14];
  const float* st_w1 = (const float*)d_in[15];
  const float* st_w2 = (const float*)d_in[16];
  const float* out_fc1_w = (const float*)d_in[17];
  const float* out_fc1_b = (const float*)d_in[18];
  const float* out_fc2_w = (const float*)d_in[19];
  const float* out_fc2_b = (const float*)d_in[20];
  float* out = (float*)d_out;

  char* p = (char*)d_ws;
  short* h = (short*)p;   p += (size_t)NN * HH * 2;
  short* hcf = (short*)p; p += (size_t)NN * HH * 2;
  float* m = (float*)p;   p += (size_t)NN * HH * 4;
  short* ebuf = (short*)p; p += (size_t)EE * HH * 2;
  auto alloc_pack = [&](int KT, int NT) {
    short* r = (short*)p;
    p += (size_t)KT * NT * 512 * 2;  // single bf16 plane
    return r;
  };
  // 32x32 packs (edge weights)
  short* p_eu0 = alloc_pack(26, 8);
  short* p_eu1[2]; for (int l = 0; l < 2; ++l) p_eu1[l] = alloc_pack(24, 8);
  short* p_fc2[3]; for (int l = 0; l < 3; ++l) p_fc2[l] = alloc_pack(16, 4);
  short* p_f1[3], *p_f2[3];
  for (int l = 0; l < 3; ++l) { p_f1[l] = alloc_pack(8, 4); p_f2[l] = alloc_pack(8, 4); }
  // 16x16 packs (node/readout weights)
  short* p_cf[3], *p_st1[3], *p_st2[3];
  for (int l = 0; l < 3; ++l) {
    p_cf[l] = alloc_pack(4, 8); p_st1[l] = alloc_pack(4, 8); p_st2[l] = alloc_pack(4, 8);
  }
  short* p_ro = alloc_pack(4, 4);

  // single fused pack launch
  PackArgs pa;
  int off = 0, nd = 0;
  auto addpack = [&](const float* src, short* dst, int Kreal, int KT, int NT, int mode) {
    off += KT * NT * 512;
    pa.d[nd].src = src; pa.d[nd].dst = dst;
    pa.d[nd].Kreal = Kreal; pa.d[nd].KT = KT; pa.d[nd].NT = NT;
    pa.d[nd].mode = mode; pa.d[nd].end = off;
    ++nd;
  };
  addpack(eu0_fc1_w, p_eu0, 406, 26, 8, 1);
  for (int l = 0; l < 2; ++l) addpack(eu_fc1_w + (size_t)l * 384 * 256, p_eu1[l], 384, 24, 8, 1);
  for (int l = 0; l < 3; ++l) addpack(eu_fc2_w + (size_t)l * 256 * 128, p_fc2[l], 256, 16, 4, 1);
  for (int l = 0; l < 3; ++l) {
    addpack(flt_w1 + (size_t)l * 16384, p_f1[l], 128, 8, 4, 1);
    addpack(flt_w2 + (size_t)l * 16384, p_f2[l], 128, 8, 4, 1);
    addpack(cf_w + (size_t)l * 16384, p_cf[l], 128, 4, 8, 0);
    addpack(st_w1 + (size_t)l * 16384, p_st1[l], 128, 4, 8, 0);
    addpack(st_w2 + (size_t)l * 16384, p_st2[l], 128, 4, 8, 0);
  }
  addpack(out_fc1_w, p_ro, 128, 4, 4, 0);
  for (int i = nd; i < 24; ++i) pa.d[i].end = off;
  packall_kernel<<<(off + 255) / 256, 256, 0, stream>>>(pa, off);

  hipMemsetAsync(d_out, 0, 16 * sizeof(float), stream);
  hipMemsetAsync(m, 0, (size_t)NN * HH * 4, stream);  // layers 0,1 re-zero m in state_kernel
  embedgemm_kernel<<<313, 512, 0, stream>>>(z, emb, p_cf[0], h, hcf);

  double stop = 15.0 - 15.0 / 150.0;       // 14.9
  double step = stop / 149.0;              // 0.1
  float gstep = (float)step;
  float gcoeff = (float)(-0.5 / (step * step));

  for (int i = 0; i < 3; ++i) {
    const short* w1p = (i == 0) ? p_eu0 : p_eu1[i - 1];
    if (i == 0)
      edge_kernel<true, true><<<4000, 512, 0, stream>>>(
          h, hcf, ei, pos, ebuf, ebuf, w1p, eu_fc1_b + (size_t)i * 256,
          p_fc2[i], eu_fc2_b + (size_t)i * 128, p_f1[i], flt_b1 + (size_t)i * 128,
          p_f2[i], flt_b2 + (size_t)i * 128, m, gcoeff, gstep);
    else if (i == 1)
      edge_kernel<false, true><<<4000, 512, 0, stream>>>(
          h, hcf, ei, pos, ebuf, ebuf, w1p, eu_fc1_b + (size_t)i * 256,
          p_fc2[i], eu_fc2_b + (size_t)i * 128, p_f1[i], flt_b1 + (size_t)i * 128,
          p_f2[i], flt_b2 + (size_t)i * 128, m, gcoeff, gstep);
    else
      edge_kernel<false, false><<<4000, 512, 0, stream>>>(
          h, hcf, ei, pos, ebuf, ebuf, w1p, eu_fc1_b + (size_t)i * 256,
          p_fc2[i], eu_fc2_b + (size_t)i * 128, p_f1[i], flt_b1 + (size_t)i * 128,
          p_f2[i], flt_b2 + (size_t)i * 128, m, gcoeff, gstep);
    if (i < 2)
      state_kernel<true><<<313, 512, 0, stream>>>(h, m, p_st1[i], p_st2[i], p_cf[i + 1], hcf);
    else
      state_kernel<false><<<313, 512, 0, stream>>>(h, m, p_st1[i], p_st2[i], nullptr, nullptr);
  }

  readout_kernel<<<157, 512, 0, stream>>>(h, batch, p_ro, out_fc1_b,
                                          out_fc2_w, out_fc2_b, out);
}

// Round 14
// 598.328 us; speedup vs baseline: 1.0649x; 1.0649x over previous
//
#include <hip/hip_runtime.h>
#include <hip/hip_bf16.h>
#include <math.h>

#define NN 20000
#define EE 256000
#define HH 128
#define NGAUSS 150

typedef __attribute__((ext_vector_type(8))) short bf16x8;
typedef __attribute__((ext_vector_type(4))) float f32x4;

__device__ __forceinline__ short f2bf(float f) {
  unsigned u = __builtin_bit_cast(unsigned, f);
  u += 0x7FFFu + ((u >> 16) & 1u);
  return (short)(u >> 16);
}
__device__ __forceinline__ float bf2f(short s) {
  unsigned u = ((unsigned)(unsigned short)s) << 16;
  return __builtin_bit_cast(float, u);
}
// cheap ShiftedSoftplus: max(x,0) + log(1+exp(-|x|)) - log2, native exp/log
__device__ __forceinline__ float sspf(float x) {
  float t = __expf(-fabsf(x));
  return fmaxf(x, 0.f) + __logf(1.f + t) - 0.69314718055994531f;
}

// ---- weight packing: [kt][nt][lane][j], single bf16 plane ----
struct PackDesc { const float* src; short* dst; int Kreal; int KT; int NT; int end; };
struct PackArgs { PackDesc d[24]; };

__global__ void packall_kernel(PackArgs a, int total) {
  int idx = blockIdx.x * 256 + threadIdx.x;
  if (idx >= total) return;
  int i = 0, start = 0;
  while (idx >= a.d[i].end) { start = a.d[i].end; ++i; }
  int local = idx - start;
  const float* src = a.d[i].src;
  short* dst = a.d[i].dst;
  int Kreal = a.d[i].Kreal, NT = a.d[i].NT;
  int j = local & 7;
  int lane = (local >> 3) & 63;
  int tile = local >> 9;
  int nt = tile % NT, kt = tile / NT;
  int k = kt * 32 + (lane >> 4) * 8 + j;
  int n = nt * 16 + (lane & 15);
  float w = (k < Kreal) ? src[(size_t)k * (NT * 16) + n] : 0.f;
  dst[local] = f2bf(w);
}

// ---- LDS-A x packed-global-B MFMA tile GEMM, single-plane, 1-deep pipeline ----
// NOTE (r9): LDS tile stride MUST be a multiple of 8 shorts (16B) or the
// b128 A-reads misalign and split (+42% measured).
template <int KT, int NTW, int JSTEP = 1>
__device__ __forceinline__ void gemm_tile(const short* __restrict__ A, int as,
                                          const short* __restrict__ pack, int ktBase,
                                          int NT, int lane, int wave,
                                          f32x4 (&acc)[NTW][4]) {
  constexpr int WSTEP = (JSTEP == 1) ? NTW : 1;
  const int arow = lane & 15, agrp = lane >> 4;
  const short* abase = A + arow * as + agrp * 8;
  const short* bbase = pack + (size_t)ktBase * NT * 512 + (size_t)lane * 8;
  const int nt0 = wave * WSTEP;
  bf16x8 af[4], bh[NTW];
#pragma unroll
  for (int rg = 0; rg < 4; ++rg) af[rg] = *(const bf16x8*)(abase + rg * 16 * as);
#pragma unroll
  for (int j = 0; j < NTW; ++j)
    bh[j] = *(const bf16x8*)(bbase + (size_t)(nt0 + j * JSTEP) * 512);
#pragma unroll
  for (int kt = 0; kt < KT; ++kt) {
    bf16x8 naf[4], nbh[NTW];
    if (kt + 1 < KT) {
#pragma unroll
      for (int rg = 0; rg < 4; ++rg)
        naf[rg] = *(const bf16x8*)(abase + rg * 16 * as + (kt + 1) * 32);
#pragma unroll
      for (int j = 0; j < NTW; ++j)
        nbh[j] = *(const bf16x8*)(bbase + (size_t)((kt + 1) * NT + nt0 + j * JSTEP) * 512);
    }
#pragma unroll
    for (int j = 0; j < NTW; ++j)
#pragma unroll
      for (int rg = 0; rg < 4; ++rg)
        acc[j][rg] = __builtin_amdgcn_mfma_f32_16x16x32_bf16(af[rg], bh[j], acc[j][rg], 0, 0, 0);
    if (kt + 1 < KT) {
#pragma unroll
      for (int rg = 0; rg < 4; ++rg) af[rg] = naf[rg];
#pragma unroll
      for (int j = 0; j < NTW; ++j) bh[j] = nbh[j];
    }
  }
}

// stage 16 f32 -> 16 bf16 (two uint4 stores)
__device__ __forceinline__ void cvt16(const float4* __restrict__ src, short* dst) {
#pragma unroll
  for (int v = 0; v < 2; ++v) {
    float4 f0 = src[2 * v], f1 = src[2 * v + 1];
    union { short s[8]; uint4 u; } tm;
    tm.s[0] = f2bf(f0.x); tm.s[1] = f2bf(f0.y); tm.s[2] = f2bf(f0.z); tm.s[3] = f2bf(f0.w);
    tm.s[4] = f2bf(f1.x); tm.s[5] = f2bf(f1.y); tm.s[6] = f2bf(f1.z); tm.s[7] = f2bf(f1.w);
    *(uint4*)(dst + v * 8) = tm.u;
  }
}

// embed + first-layer cf nodegemm fused: h = bf16(emb[z]); hcf = h @ cf0
__global__ __launch_bounds__(512, 4) void embedgemm_kernel(
    const int* __restrict__ z, const float* __restrict__ emb,
    const short* __restrict__ pk, short* __restrict__ h, short* __restrict__ hcf) {
  __shared__ short A[64 * 136];
  const int t = threadIdx.x, wave = t >> 6, lane = t & 63;
  const int arow = lane & 15, agrp = lane >> 4;
  const int n0 = blockIdx.x * 64;
  {
    int el = t >> 3, q = t & 7;
    int n = n0 + el;
    short* dst = A + el * 136 + q * 16;
    if (n < NN) {
      const float4* src = (const float4*)(emb + (size_t)z[n] * HH + q * 16);
      union { short s[16]; uint4 u[2]; } tm;
#pragma unroll
      for (int v = 0; v < 2; ++v) {
        float4 f0 = src[2 * v], f1 = src[2 * v + 1];
        tm.s[v * 8 + 0] = f2bf(f0.x); tm.s[v * 8 + 1] = f2bf(f0.y);
        tm.s[v * 8 + 2] = f2bf(f0.z); tm.s[v * 8 + 3] = f2bf(f0.w);
        tm.s[v * 8 + 4] = f2bf(f1.x); tm.s[v * 8 + 5] = f2bf(f1.y);
        tm.s[v * 8 + 6] = f2bf(f1.z); tm.s[v * 8 + 7] = f2bf(f1.w);
      }
      *(uint4*)dst = tm.u[0]; *(uint4*)(dst + 8) = tm.u[1];
      uint4* hg = (uint4*)(h + (size_t)n * HH + q * 16);
      hg[0] = tm.u[0]; hg[1] = tm.u[1];
    } else {
      uint4 zz = {0u, 0u, 0u, 0u};
      *(uint4*)dst = zz; *(uint4*)(dst + 8) = zz;
    }
  }
  __syncthreads();
  f32x4 zv = {0.f, 0.f, 0.f, 0.f};
  f32x4 acc[1][4];
#pragma unroll
  for (int rg = 0; rg < 4; ++rg) acc[0][rg] = zv;
  gemm_tile<4, 1>(A, 136, pk, 0, 8, lane, wave, acc);
  int col = wave * 16 + arow;
#pragma unroll
  for (int rg = 0; rg < 4; ++rg)
#pragma unroll
    for (int r = 0; r < 4; ++r) {
      int n = n0 + rg * 16 + agrp * 4 + r;
      if (n < NN) hcf[(size_t)n * HH + col] = f2bf(acc[0][rg][r]);
    }
}

// h += ssp(m @ st1) @ st2 ; optionally fused hcf = h_new @ cf_{i+1}
// FUSE also re-zeroes m in place of a separate memset
template <bool FUSE>
__global__ __launch_bounds__(512, 4) void state_kernel(
    short* __restrict__ h, float* __restrict__ m,
    const short* __restrict__ p1, const short* __restrict__ p2,
    const short* __restrict__ pcf, short* __restrict__ hcf) {
  __shared__ short A[64 * 136];
  __shared__ short T[64 * 136];
  const int t = threadIdx.x, wave = t >> 6, lane = t & 63;
  const int arow = lane & 15, agrp = lane >> 4;
  const int n0 = blockIdx.x * 64;
  {
    int el = t >> 3, q = t & 7;
    int n = n0 + el;
    short* dst = A + el * 136 + q * 16;
    if (n < NN) {
      float* msrc = m + (size_t)n * HH + q * 16;
      cvt16((const float4*)msrc, dst);
      if (FUSE) {
        float4 z4 = {0.f, 0.f, 0.f, 0.f};
        float4* mz = (float4*)msrc;
        mz[0] = z4; mz[1] = z4; mz[2] = z4; mz[3] = z4;
      }
    } else {
      uint4 zz = {0u, 0u, 0u, 0u};
      *(uint4*)dst = zz; *(uint4*)(dst + 8) = zz;
    }
  }
  __syncthreads();
  f32x4 zv = {0.f, 0.f, 0.f, 0.f};
  f32x4 acc[1][4];
#pragma unroll
  for (int rg = 0; rg < 4; ++rg) acc[0][rg] = zv;
  gemm_tile<4, 1>(A, 136, p1, 0, 8, lane, wave, acc);
  int col = wave * 16 + arow;
#pragma unroll
  for (int rg = 0; rg < 4; ++rg)
#pragma unroll
    for (int r = 0; r < 4; ++r) {
      int rowl = rg * 16 + agrp * 4 + r;
      T[rowl * 136 + col] = f2bf(sspf(acc[0][rg][r]));
    }
  __syncthreads();
  // hoist residual h loads (latency cover for the p2 gemm)
  short hold[16];
#pragma unroll
  for (int rg = 0; rg < 4; ++rg)
#pragma unroll
    for (int r = 0; r < 4; ++r) {
      int n = n0 + rg * 16 + agrp * 4 + r;
      hold[rg * 4 + r] = (n < NN) ? h[(size_t)n * HH + col] : (short)0;
    }
  f32x4 acc2[1][4];
#pragma unroll
  for (int rg = 0; rg < 4; ++rg) acc2[0][rg] = zv;
  gemm_tile<4, 1>(T, 136, p2, 0, 8, lane, wave, acc2);
#pragma unroll
  for (int rg = 0; rg < 4; ++rg)
#pragma unroll
    for (int r = 0; r < 4; ++r) {
      int rowl = rg * 16 + agrp * 4 + r;
      int n = n0 + rowl;
      short nb = f2bf(bf2f(hold[rg * 4 + r]) + acc2[0][rg][r]);
      if (n < NN) h[(size_t)n * HH + col] = nb;
      if (FUSE) A[rowl * 136 + col] = (n < NN) ? nb : (short)0;
    }
  if (FUSE) {
    __syncthreads();
    f32x4 acc3[1][4];
#pragma unroll
    for (int rg = 0; rg < 4; ++rg) acc3[0][rg] = zv;
    gemm_tile<4, 1>(A, 136, pcf, 0, 8, lane, wave, acc3);
#pragma unroll
    for (int rg = 0; rg < 4; ++rg)
#pragma unroll
      for (int r = 0; r < 4; ++r) {
        int n = n0 + rg * 16 + agrp * 4 + r;
        if (n < NN) hcf[(size_t)n * HH + col] = f2bf(acc3[0][rg][r]);
      }
  }
}

// fused per-layer edge pipeline: single-plane weights, 7 barriers (vs r12's 13),
// dual-buffer fc1 staging + issue-early/write-late e-gather.
// ALL LDS strides 16B-aligned (r7's version of this had ACT=140 misaligned —
// that, per r9's measurement, was its regression; retry aligned).
template <bool L0, bool WRITE_E>
__global__ __launch_bounds__(512, 4) void edge_kernel(
    const short* __restrict__ h, const short* __restrict__ hcf,
    const int* __restrict__ ei, const float* __restrict__ pos,
    const short* __restrict__ ein, short* __restrict__ eout,
    const short* __restrict__ w1p, const float* __restrict__ b1,
    const short* __restrict__ w2p, const float* __restrict__ b2,
    const short* __restrict__ f1p, const float* __restrict__ fb1,
    const short* __restrict__ f2p, const float* __restrict__ fb2,
    float* __restrict__ m, float gcoeff, float gstep) {
  __shared__ short SBUF[64 * 168];  // h[col]/gauss-e staging (168); e-values (136)
  __shared__ short BUF1[64 * 136];  // h[row] staging; later fc1 half-1 activations
  __shared__ short ACT[64 * 136];   // fc1 half-0 activations; filter1 output
  __shared__ int RIDX[64], CIDX[64];
  const int t = threadIdx.x;
  const int wave = t >> 6, lane = t & 63;
  const int arow = lane & 15, agrp = lane >> 4;
  const int e0 = blockIdx.x * 64;

  if (t < 64) RIDX[t] = ei[e0 + t];
  else if (t < 128) CIDX[t - 64] = ei[EE + e0 + t - 64];
  __syncthreads();                                            // B1

  const int el = t >> 3, q = t & 7;
  f32x4 zv = {0.f, 0.f, 0.f, 0.f};
  f32x4 acc1[2][4];   // [half][rg] ; nt = wave + 8*half
#pragma unroll
  for (int j = 0; j < 2; ++j)
#pragma unroll
    for (int rg = 0; rg < 4; ++rg) acc1[j][rg] = zv;

  // ---- fc1 staging: both node gathers issued back-to-back (one latency) ----
  {
    const uint4* csrc = (const uint4*)(h + (size_t)CIDX[el] * HH + q * 16);
    const uint4* rsrc = (const uint4*)(h + (size_t)RIDX[el] * HH + q * 16);
    uint4 c0 = csrc[0], c1 = csrc[1];
    uint4 r0 = rsrc[0], r1 = rsrc[1];
    uint4* cdst = (uint4*)(SBUF + el * 168 + q * 16);
    uint4* rdst = (uint4*)(BUF1 + el * 136 + q * 16);
    cdst[0] = c0; cdst[1] = c1;
    rdst[0] = r0; rdst[1] = r1;
  }
  __syncthreads();                                            // B2
  gemm_tile<4, 2, 8>(SBUF, 168, w1p, 0, 16, lane, wave, acc1);
  __syncthreads();                                            // B3 (SBUF free)

  // issue e-gather / pos loads EARLY; compute h[row] gemm; write LATE
  uint4 eva, evb;
  float pxr, pyr, pzr, pxc, pyc, pzc;
  if (L0) {
    int rn = RIDX[el], cn = CIDX[el];
    pxr = pos[rn * 3 + 0]; pyr = pos[rn * 3 + 1]; pzr = pos[rn * 3 + 2];
    pxc = pos[cn * 3 + 0]; pyc = pos[cn * 3 + 1]; pzc = pos[cn * 3 + 2];
  } else {
    const uint4* esrc = (const uint4*)(ein + (size_t)(e0 + el) * HH + q * 16);
    eva = esrc[0]; evb = esrc[1];
  }
  gemm_tile<4, 2, 8>(BUF1, 136, w1p, 4, 16, lane, wave, acc1);
  if (L0) {
    float dx = pxr - pxc, dy = pyr - pyc, dz = pzr - pzc;
    float d = sqrtf(dx * dx + dy * dy + dz * dz);
#pragma unroll
    for (int i2 = 0; i2 < 20; ++i2) {
      int k = q * 20 + i2;
      float val = 0.f;
      if (k < NGAUSS) { float u = d - (float)k * gstep; val = __expf(gcoeff * u * u); }
      SBUF[el * 168 + k] = f2bf(val);
    }
  } else {
    uint4* dst = (uint4*)(SBUF + el * 168 + q * 16);
    dst[0] = eva; dst[1] = evb;
  }
  __syncthreads();                                            // B4
  if (L0)
    gemm_tile<5, 2, 8>(SBUF, 168, w1p, 8, 16, lane, wave, acc1);
  else
    gemm_tile<4, 2, 8>(SBUF, 168, w1p, 8, 16, lane, wave, acc1);

  const int col = wave * 16 + arow;  // 0..127 (within a half)

  // ---- fc1 epilogue: half0 -> ACT, half1 -> BUF1; ONE sync; two acc gemms ----
  {
    float bias0 = b1[col], bias1 = b1[128 + col];
#pragma unroll
    for (int rg = 0; rg < 4; ++rg)
#pragma unroll
      for (int r = 0; r < 4; ++r) {
        int rowl = rg * 16 + agrp * 4 + r;
        ACT[rowl * 136 + col] = f2bf(sspf(acc1[0][rg][r] + bias0));
        BUF1[rowl * 136 + col] = f2bf(sspf(acc1[1][rg][r] + bias1));
      }
  }
  __syncthreads();                                            // B5
  f32x4 acc2[1][4];
#pragma unroll
  for (int rg = 0; rg < 4; ++rg) acc2[0][rg] = zv;
  gemm_tile<4, 1>(ACT, 136, w2p, 0, 8, lane, wave, acc2);
  gemm_tile<4, 1>(BUF1, 136, w2p, 4, 8, lane, wave, acc2);

  // ---- e epilogue: write e to global (if needed) and SBUF (stride 136) ----
  {
    float bias = b2[col];
#pragma unroll
    for (int rg = 0; rg < 4; ++rg)
#pragma unroll
      for (int r = 0; r < 4; ++r) {
        int rowl = rg * 16 + agrp * 4 + r;
        float ev = acc2[0][rg][r] + bias;
        short eb = f2bf(ev);
        if (WRITE_E) eout[(size_t)(e0 + rowl) * HH + col] = eb;
        SBUF[rowl * 136 + col] = eb;
      }
  }
  // hoist hcf gather (used only in filter2 epilogue -> covered by filter1 gemm)
  short hvreg[16];
#pragma unroll
  for (int rg = 0; rg < 4; ++rg)
#pragma unroll
    for (int r = 0; r < 4; ++r) {
      int rowl = rg * 16 + agrp * 4 + r;
      hvreg[rg * 4 + r] = hcf[(size_t)RIDX[rowl] * HH + col];
    }
  __syncthreads();                                            // B6

  // ---- filter1: 128->128, ssp -> ACT ----
  f32x4 acc3[1][4];
#pragma unroll
  for (int rg = 0; rg < 4; ++rg) acc3[0][rg] = zv;
  gemm_tile<4, 1>(SBUF, 136, f1p, 0, 8, lane, wave, acc3);
  {
    float bias = fb1[col];
#pragma unroll
    for (int rg = 0; rg < 4; ++rg)
#pragma unroll
      for (int r = 0; r < 4; ++r) {
        int rowl = rg * 16 + agrp * 4 + r;
        ACT[rowl * 136 + col] = f2bf(sspf(acc3[0][rg][r] + bias));
      }
  }
  __syncthreads();                                            // B7

  // ---- filter2 + modulate + scatter ----
  f32x4 acc4[1][4];
#pragma unroll
  for (int rg = 0; rg < 4; ++rg) acc4[0][rg] = zv;
  gemm_tile<4, 1>(ACT, 136, f2p, 0, 8, lane, wave, acc4);
  {
    float bias = fb2[col];
#pragma unroll
    for (int rg = 0; rg < 4; ++rg)
#pragma unroll
      for (int r = 0; r < 4; ++r) {
        int rowl = rg * 16 + agrp * 4 + r;
        float wv = sspf(acc4[0][rg][r] + bias);
        float hv = bf2f(hvreg[rg * 4 + r]);
        atomicAdd(&m[(size_t)CIDX[rowl] * HH + col], wv * hv);
      }
  }
}

// readout: MFMA per 128-node tile; per-batch LDS accumulation; <=16 global atomics/block
__global__ __launch_bounds__(512, 2) void readout_kernel(
    const short* __restrict__ h, const int* __restrict__ batch,
    const short* __restrict__ pro, const float* __restrict__ b1,
    const float* __restrict__ w2, const float* __restrict__ b2,
    float* __restrict__ out) {
  __shared__ char RAW[128 * 272];  // A[128][136] bf16, later VAL[128][68] f32
  __shared__ float bacc[16];
  short* A = (short*)RAW;
  float* VAL = (float*)RAW;
  const int t = threadIdx.x, wave = t >> 6, lane = t & 63;
  const int arow = lane & 15, agrp = lane >> 4;
  const int n0 = blockIdx.x * 128;
  if (t < 16) bacc[t] = 0.f;
  {
    int row = t >> 2, qq = t & 3;
    int n = n0 + row;
    uint4* dst = (uint4*)(A + row * 136);
    if (n < NN) {
      const uint4* src = (const uint4*)(h + (size_t)n * HH);
#pragma unroll
      for (int v = 0; v < 4; ++v) dst[qq * 4 + v] = src[qq * 4 + v];
    } else {
      uint4 zz = {0u, 0u, 0u, 0u};
#pragma unroll
      for (int v = 0; v < 4; ++v) dst[qq * 4 + v] = zz;
    }
  }
  __syncthreads();
  f32x4 zv = {0.f, 0.f, 0.f, 0.f};
  f32x4 acc[1][4];
#pragma unroll
  for (int rg = 0; rg < 4; ++rg) acc[0][rg] = zv;
  const short* Abase = A + (wave >> 2) * 64 * 136;
  gemm_tile<4, 1>(Abase, 136, pro, 0, 4, lane, wave & 3, acc);
  __syncthreads();  // A dead; VAL aliases it
  {
    int col = (wave & 3) * 16 + arow;
    float bias = b1[col], wv2 = w2[col];
#pragma unroll
    for (int rg = 0; rg < 4; ++rg)
#pragma unroll
      for (int r = 0; r < 4; ++r) {
        int row = (wave >> 2) * 64 + rg * 16 + agrp * 4 + r;
        VAL[row * 68 + col] = sspf(acc[0][rg][r] + bias) * wv2;
      }
  }
  __syncthreads();
  if (t < 128) {
    int n = n0 + t;
    if (n < NN) {
      float s = 0.f;
#pragma unroll 8
      for (int c = 0; c < 64; ++c) s += VAL[t * 68 + c];
      atomicAdd(&bacc[batch[n]], s + b2[0]);
    }
  }
  __syncthreads();
  if (t < 16 && bacc[t] != 0.f) atomicAdd(&out[t], bacc[t]);
}

extern "C" void kernel_launch(void* const* d_in, const int* in_sizes, int n_in,
                              void* d_out, int out_size, void* d_ws, size_t ws_size,
                              hipStream_t stream) {
  const int* z = (const int*)d_in[0];
  const float* pos = (const float*)d_in[1];
  const int* batch = (const int*)d_in[2];
  const int* ei = (const int*)d_in[3];
  const float* emb = (const float*)d_in[4];
  const float* eu0_fc1_w = (const float*)d_in[5];
  const float* eu_fc1_w = (const float*)d_in[6];
  const float* eu_fc1_b = (const float*)d_in[7];
  const float* eu_fc2_w = (const float*)d_in[8];
  const float* eu_fc2_b = (const float*)d_in[9];
  const float* flt_w1 = (const float*)d_in[10];
  const float* flt_b1 = (const float*)d_in[11];
  const float* flt_w2 = (const float*)d_in[12];
  const float* flt_b2 = (const float*)d_in[13];
  const float* cf_w = (const float*)d_in[14];
  const float* st_w1 = (const float*)d_in[15];
  const float* st_w2 = (const float*)d_in[16];
  const float* out_fc1_w = (const float*)d_in[17];
  const float* out_fc1_b = (const float*)d_in[18];
  const float* out_fc2_w = (const float*)d_in[19];
  const float* out_fc2_b = (const float*)d_in[20];
  float* out = (float*)d_out;

  char* p = (char*)d_ws;
  short* h = (short*)p;   p += (size_t)NN * HH * 2;
  short* hcf = (short*)p; p += (size_t)NN * HH * 2;
  float* m = (float*)p;   p += (size_t)NN * HH * 4;
  short* ebuf = (short*)p; p += (size_t)EE * HH * 2;
  auto alloc_pack = [&](int KT, int NT) {
    short* r = (short*)p;
    p += (size_t)KT * NT * 512 * 2;  // single bf16 plane
    return r;
  };
  short* p_eu0 = alloc_pack(13, 16);
  short* p_eu1[2]; for (int l = 0; l < 2; ++l) p_eu1[l] = alloc_pack(12, 16);
  short* p_fc2[3]; for (int l = 0; l < 3; ++l) p_fc2[l] = alloc_pack(8, 8);
  short* p_f1[3], *p_f2[3], *p_cf[3], *p_st1[3], *p_st2[3];
  for (int l = 0; l < 3; ++l) {
    p_f1[l] = alloc_pack(4, 8); p_f2[l] = alloc_pack(4, 8);
    p_cf[l] = alloc_pack(4, 8); p_st1[l] = alloc_pack(4, 8); p_st2[l] = alloc_pack(4, 8);
  }
  short* p_ro = alloc_pack(4, 4);

  // single fused pack launch
  PackArgs pa;
  int off = 0, nd = 0;
  auto addpack = [&](const float* src, short* dst, int Kreal, int KT, int NT) {
    off += KT * NT * 512;
    pa.d[nd].src = src; pa.d[nd].dst = dst;
    pa.d[nd].Kreal = Kreal; pa.d[nd].KT = KT; pa.d[nd].NT = NT; pa.d[nd].end = off;
    ++nd;
  };
  addpack(eu0_fc1_w, p_eu0, 406, 13, 16);
  for (int l = 0; l < 2; ++l) addpack(eu_fc1_w + (size_t)l * 384 * 256, p_eu1[l], 384, 12, 16);
  for (int l = 0; l < 3; ++l) addpack(eu_fc2_w + (size_t)l * 256 * 128, p_fc2[l], 256, 8, 8);
  for (int l = 0; l < 3; ++l) {
    addpack(flt_w1 + (size_t)l * 16384, p_f1[l], 128, 4, 8);
    addpack(flt_w2 + (size_t)l * 16384, p_f2[l], 128, 4, 8);
    addpack(cf_w + (size_t)l * 16384, p_cf[l], 128, 4, 8);
    addpack(st_w1 + (size_t)l * 16384, p_st1[l], 128, 4, 8);
    addpack(st_w2 + (size_t)l * 16384, p_st2[l], 128, 4, 8);
  }
  addpack(out_fc1_w, p_ro, 128, 4, 4);
  for (int i = nd; i < 24; ++i) pa.d[i].end = off;
  packall_kernel<<<(off + 255) / 256, 256, 0, stream>>>(pa, off);

  hipMemsetAsync(d_out, 0, 16 * sizeof(float), stream);
  hipMemsetAsync(m, 0, (size_t)NN * HH * 4, stream);  // layers 0,1 re-zero m in state_kernel
  embedgemm_kernel<<<313, 512, 0, stream>>>(z, emb, p_cf[0], h, hcf);

  double stop = 15.0 - 15.0 / 150.0;       // 14.9
  double step = stop / 149.0;              // 0.1
  float gstep = (float)step;
  float gcoeff = (float)(-0.5 / (step * step));

  for (int i = 0; i < 3; ++i) {
    const short* w1p = (i == 0) ? p_eu0 : p_eu1[i - 1];
    if (i == 0)
      edge_kernel<true, true><<<4000, 512, 0, stream>>>(
          h, hcf, ei, pos, ebuf, ebuf, w1p, eu_fc1_b + (size_t)i * 256,
          p_fc2[i], eu_fc2_b + (size_t)i * 128, p_f1[i], flt_b1 + (size_t)i * 128,
          p_f2[i], flt_b2 + (size_t)i * 128, m, gcoeff, gstep);
    else if (i == 1)
      edge_kernel<false, true><<<4000, 512, 0, stream>>>(
          h, hcf, ei, pos, ebuf, ebuf, w1p, eu_fc1_b + (size_t)i * 256,
          p_fc2[i], eu_fc2_b + (size_t)i * 128, p_f1[i], flt_b1 + (size_t)i * 128,
          p_f2[i], flt_b2 + (size_t)i * 128, m, gcoeff, gstep);
    else
      edge_kernel<false, false><<<4000, 512, 0, stream>>>(
          h, hcf, ei, pos, ebuf, ebuf, w1p, eu_fc1_b + (size_t)i * 256,
          p_fc2[i], eu_fc2_b + (size_t)i * 128, p_f1[i], flt_b1 + (size_t)i * 128,
          p_f2[i], flt_b2 + (size_t)i * 128, m, gcoeff, gstep);
    if (i < 2)
      state_kernel<true><<<313, 512, 0, stream>>>(h, m, p_st1[i], p_st2[i], p_cf[i + 1], hcf);
    else
      state_kernel<false><<<313, 512, 0, stream>>>(h, m, p_st1[i], p_st2[i], nullptr, nullptr);
  }

  readout_kernel<<<157, 512, 0, stream>>>(h, batch, p_ro, out_fc1_b,
                                          out_fc2_w, out_fc2_b, out);
}